// Round 1
// baseline (2580.411 us; speedup 1.0000x reference)
//
#include <hip/hip_runtime.h>
#include <math.h>

#define N_WORD 50000
#define N_DOC  10000
#define E_WW   800000
#define E_WD   320000
#define D_IN   256
#define D_H    128

// ---------------- SGEMM: C[M,N] = A[M,K] @ B[K,N], row-major, fp32 ----------
// BM=BN=64, BK=16, 256 threads, 4x4 micro-tile per thread.
#define BM 64
#define BN 64
#define BK 16

__global__ __launch_bounds__(256) void sgemm_kernel(const float* __restrict__ A,
    const float* __restrict__ B, float* __restrict__ C, int M, int N, int K) {
  __shared__ float As[BK][BM + 1];   // +1 pad to break store conflicts
  __shared__ float Bs[BK][BN];
  const int tid = threadIdx.x;
  const int bm = blockIdx.y * BM;
  const int bn = blockIdx.x * BN;
  const int trow = (tid >> 4) << 2;   // 0..60
  const int tcol = (tid & 15) << 2;   // 0..60
  const int aRow = tid >> 2;          // 0..63
  const int aK   = (tid & 3) << 2;    // 0,4,8,12
  const int bK   = tid >> 4;          // 0..15
  const int bCol = (tid & 15) << 2;   // 0..60
  const bool aValid = (bm + aRow) < M;
  const int aRowC = aValid ? (bm + aRow) : (M - 1);   // clamp, value unused when invalid
  const float* Aptr = A + (size_t)aRowC * K + aK;
  const float* Bptr = B + (size_t)bK * N + bn + bCol;

  float acc[4][4] = {};
  for (int k0 = 0; k0 < K; k0 += BK) {
    float4 av = make_float4(0.f, 0.f, 0.f, 0.f);
    if (aValid) av = *(const float4*)(Aptr + k0);
    float4 bv = *(const float4*)(Bptr + (size_t)k0 * N);
    As[aK + 0][aRow] = av.x;
    As[aK + 1][aRow] = av.y;
    As[aK + 2][aRow] = av.z;
    As[aK + 3][aRow] = av.w;
    *(float4*)&Bs[bK][bCol] = bv;
    __syncthreads();
#pragma unroll
    for (int k = 0; k < BK; ++k) {
      float ar[4], br[4];
#pragma unroll
      for (int i = 0; i < 4; ++i) ar[i] = As[k][trow + i];
#pragma unroll
      for (int j = 0; j < 4; ++j) br[j] = Bs[k][tcol + j];
#pragma unroll
      for (int i = 0; i < 4; ++i)
#pragma unroll
        for (int j = 0; j < 4; ++j) acc[i][j] += ar[i] * br[j];
    }
    __syncthreads();
  }
#pragma unroll
  for (int i = 0; i < 4; ++i) {
    int m = bm + trow + i;
    if (m < M) {
      float4 o = make_float4(acc[i][0], acc[i][1], acc[i][2], acc[i][3]);
      *(float4*)(C + (size_t)m * N + bn + tcol) = o;
    }
  }
}

// ---------------- degree / small helpers -----------------------------------
__global__ void count_deg_kernel(const int* __restrict__ dst, int* __restrict__ deg, int E) {
  int i = blockIdx.x * blockDim.x + threadIdx.x;
  if (i < E) atomicAdd(&deg[dst[i]], 1);
}

__global__ void inv_deg_kernel(const int* __restrict__ deg, float* __restrict__ inv, int n) {
  int i = blockIdx.x * blockDim.x + threadIdx.x;
  if (i < n) {
    int d = deg[i];
    inv[i] = 1.0f / (float)(d > 1 ? d : 1);
  }
}

__global__ void add3_kernel(const float* __restrict__ a, const float* __restrict__ b,
                            const float* __restrict__ c, float* __restrict__ o, int n) {
  int i = blockIdx.x * blockDim.x + threadIdx.x;
  if (i < n) o[i] = a[i] + b[i] + c[i];
}

// t[dst] += y[src] * inv_deg[dst]  (pre-scaled mean, accumulated across relations)
__global__ void scatter_kernel(const float* __restrict__ y, const int* __restrict__ src,
                               const int* __restrict__ dst, const float* __restrict__ inv,
                               float* __restrict__ t, int E) {
  int e = blockIdx.x * 2 + (threadIdx.x >> 7);
  int c = threadIdx.x & 127;
  if (e < E) {
    int s = src[e], d = dst[e];
    atomicAdd(&t[(size_t)d * D_H + c], y[(size_t)s * D_H + c] * inv[d]);
  }
}

__global__ void bias_relu_kernel(const float* __restrict__ t, float* __restrict__ o,
                                 const float* __restrict__ b, int n) {
  int i = blockIdx.x * blockDim.x + threadIdx.x;
  if (i < n) {
    float v = t[i] + b[i & (D_H - 1)];
    o[i] = v > 0.f ? v : 0.f;
  }
}

// out[v] = sigmoid(dot(x[v], lin_w) + lin_b); one wave (64 lanes) per node
__global__ void final_kernel(const float* __restrict__ xw, const float* __restrict__ xd,
                             const float* __restrict__ lw, const float* __restrict__ lb,
                             float* __restrict__ out) {
  int wid = (blockIdx.x * blockDim.x + threadIdx.x) >> 6;
  int lane = threadIdx.x & 63;
  if (wid >= N_WORD + N_DOC) return;
  const float* x = (wid < N_WORD) ? xw + (size_t)wid * D_H
                                  : xd + (size_t)(wid - N_WORD) * D_H;
  float s = x[lane] * lw[lane] + x[lane + 64] * lw[lane + 64];
#pragma unroll
  for (int off = 32; off > 0; off >>= 1) s += __shfl_down(s, off);
  if (lane == 0) out[wid] = 1.0f / (1.0f + expf(-(s + lb[0])));
}

// ---------------------------------------------------------------------------
extern "C" void kernel_launch(void* const* d_in, const int* in_sizes, int n_in,
                              void* d_out, int out_size, void* d_ws, size_t ws_size,
                              hipStream_t stream) {
  const float* xw      = (const float*)d_in[0];
  const float* xd      = (const float*)d_in[1];
  const int*   ww_src  = (const int*)d_in[2];
  const int*   ww_dst  = (const int*)d_in[3];
  const int*   wwr_src = (const int*)d_in[4];
  const int*   wwr_dst = (const int*)d_in[5];
  const int*   wd_src  = (const int*)d_in[6];
  const int*   wd_dst  = (const int*)d_in[7];
  const int*   wdr_src = (const int*)d_in[8];
  const int*   wdr_dst = (const int*)d_in[9];
  const float* Ws1     = (const float*)d_in[10];  // [4,256,128]
  const float* Wn1     = (const float*)d_in[11];  // [4,256,128]
  const float* b1      = (const float*)d_in[12];  // [4,128]
  const float* Ws2     = (const float*)d_in[13];  // [4,128,128]
  const float* Wn2     = (const float*)d_in[14];  // [4,128,128]
  const float* b2      = (const float*)d_in[15];  // [4,128]
  const float* lin_w   = (const float*)d_in[16];  // [1,128]
  const float* lin_b   = (const float*)d_in[17];  // [1]
  float* out = (float*)d_out;

  // ---- workspace carve (~96 MB total) ----
  char* p = (char*)d_ws;
  auto alloc = [&](size_t nbytes) {
    char* r = p;
    p += (nbytes + 255) & ~(size_t)255;
    return r;
  };
  float* y      = (float*)alloc((size_t)N_WORD * D_H * 4);  // transformed src feats (word)
  float* yd     = (float*)alloc((size_t)N_DOC * D_H * 4);   // transformed src feats (doc)
  float* t_word = (float*)alloc((size_t)N_WORD * D_H * 4);  // accumulator (word)
  float* t_doc  = (float*)alloc((size_t)N_DOC * D_H * 4);   // accumulator (doc)
  float* xw1    = (float*)alloc((size_t)N_WORD * D_H * 4);  // layer-1 word out
  float* xd1    = (float*)alloc((size_t)N_DOC * D_H * 4);   // layer-1 doc out
  float* Sw1    = (float*)alloc((size_t)D_IN * D_H * 4);    // Ws1[0]+Ws1[1]+Ws1[3]
  float* Sw2    = (float*)alloc((size_t)D_H * D_H * 4);     // Ws2[0]+Ws2[1]+Ws2[3]
  float* bs1    = (float*)alloc(D_H * 4);
  float* bs2    = (float*)alloc(D_H * 4);
  float* inv_ww  = (float*)alloc((size_t)N_WORD * 4);
  float* inv_wwr = (float*)alloc((size_t)N_WORD * 4);
  float* inv_wdr = (float*)alloc((size_t)N_WORD * 4);
  float* inv_wd  = (float*)alloc((size_t)N_DOC * 4);
  int* deg = (int*)alloc((size_t)(3 * N_WORD + N_DOC) * 4);
  int* deg_ww  = deg;
  int* deg_wwr = deg + N_WORD;
  int* deg_wdr = deg + 2 * N_WORD;
  int* deg_wd  = deg + 3 * N_WORD;

  // ---- degrees (same for both layers) ----
  hipMemsetAsync(deg, 0, (size_t)(3 * N_WORD + N_DOC) * 4, stream);
  count_deg_kernel<<<(E_WW + 255) / 256, 256, 0, stream>>>(ww_dst, deg_ww, E_WW);
  count_deg_kernel<<<(E_WW + 255) / 256, 256, 0, stream>>>(wwr_dst, deg_wwr, E_WW);
  count_deg_kernel<<<(E_WD + 255) / 256, 256, 0, stream>>>(wdr_dst, deg_wdr, E_WD);
  count_deg_kernel<<<(E_WD + 255) / 256, 256, 0, stream>>>(wd_dst, deg_wd, E_WD);
  inv_deg_kernel<<<(N_WORD + 255) / 256, 256, 0, stream>>>(deg_ww, inv_ww, N_WORD);
  inv_deg_kernel<<<(N_WORD + 255) / 256, 256, 0, stream>>>(deg_wwr, inv_wwr, N_WORD);
  inv_deg_kernel<<<(N_WORD + 255) / 256, 256, 0, stream>>>(deg_wdr, inv_wdr, N_WORD);
  inv_deg_kernel<<<(N_DOC + 255) / 256, 256, 0, stream>>>(deg_wd, inv_wd, N_DOC);

  // ---- combined self-weights / biases for word target (rel 0,1,3) ----
  add3_kernel<<<(D_IN * D_H + 255) / 256, 256, 0, stream>>>(
      Ws1, Ws1 + 1 * D_IN * D_H, Ws1 + 3 * D_IN * D_H, Sw1, D_IN * D_H);
  add3_kernel<<<1, 128, 0, stream>>>(b1, b1 + 128, b1 + 384, bs1, 128);
  add3_kernel<<<(D_H * D_H + 255) / 256, 256, 0, stream>>>(
      Ws2, Ws2 + 1 * D_H * D_H, Ws2 + 3 * D_H * D_H, Sw2, D_H * D_H);
  add3_kernel<<<1, 128, 0, stream>>>(b2, b2 + 128, b2 + 384, bs2, 128);

  auto gemm = [&](const float* A, const float* Bm, float* C, int M, int N, int K) {
    dim3 grid((N + BN - 1) / BN, (M + BM - 1) / BM);
    sgemm_kernel<<<grid, dim3(256), 0, stream>>>(A, Bm, C, M, N, K);
  };
  auto scatter = [&](const float* ysrc, const int* s, const int* d, const float* inv,
                     float* t, int E) {
    scatter_kernel<<<(E + 1) / 2, 256, 0, stream>>>(ysrc, s, d, inv, t, E);
  };

  const int WW1 = D_IN * D_H;  // 32768, per-relation weight stride layer 1
  const int WW2 = D_H * D_H;   // 16384, layer 2

  // ================= layer 1 =================
  gemm(xw, Sw1, t_word, N_WORD, D_H, D_IN);            // self terms (word)
  gemm(xw, Wn1 + 0 * WW1, y, N_WORD, D_H, D_IN);       // ww neigh transform
  scatter(y, ww_src, ww_dst, inv_ww, t_word, E_WW);
  gemm(xw, Wn1 + 1 * WW1, y, N_WORD, D_H, D_IN);       // wwr
  scatter(y, wwr_src, wwr_dst, inv_wwr, t_word, E_WW);
  gemm(xd, Wn1 + 3 * WW1, yd, N_DOC, D_H, D_IN);       // wdr (doc -> word)
  scatter(yd, wdr_src, wdr_dst, inv_wdr, t_word, E_WD);
  gemm(xd, Ws1 + 2 * WW1, t_doc, N_DOC, D_H, D_IN);    // self term (doc)
  gemm(xw, Wn1 + 2 * WW1, y, N_WORD, D_H, D_IN);       // wd (word -> doc)
  scatter(y, wd_src, wd_dst, inv_wd, t_doc, E_WD);
  bias_relu_kernel<<<(N_WORD * D_H + 255) / 256, 256, 0, stream>>>(t_word, xw1, bs1,
                                                                   N_WORD * D_H);
  bias_relu_kernel<<<(N_DOC * D_H + 255) / 256, 256, 0, stream>>>(t_doc, xd1, b1 + 256,
                                                                  N_DOC * D_H);

  // ================= layer 2 =================
  gemm(xw1, Sw2, t_word, N_WORD, D_H, D_H);
  gemm(xw1, Wn2 + 0 * WW2, y, N_WORD, D_H, D_H);
  scatter(y, ww_src, ww_dst, inv_ww, t_word, E_WW);
  gemm(xw1, Wn2 + 1 * WW2, y, N_WORD, D_H, D_H);
  scatter(y, wwr_src, wwr_dst, inv_wwr, t_word, E_WW);
  gemm(xd1, Wn2 + 3 * WW2, yd, N_DOC, D_H, D_H);
  scatter(yd, wdr_src, wdr_dst, inv_wdr, t_word, E_WD);
  gemm(xd1, Ws2 + 2 * WW2, t_doc, N_DOC, D_H, D_H);
  gemm(xw1, Wn2 + 2 * WW2, y, N_WORD, D_H, D_H);
  scatter(y, wd_src, wd_dst, inv_wd, t_doc, E_WD);
  // xw2 reuses y, xd2 reuses yd (both dead after the scatters above)
  bias_relu_kernel<<<(N_WORD * D_H + 255) / 256, 256, 0, stream>>>(t_word, y, bs2,
                                                                   N_WORD * D_H);
  bias_relu_kernel<<<(N_DOC * D_H + 255) / 256, 256, 0, stream>>>(t_doc, yd, b2 + 256,
                                                                  N_DOC * D_H);

  // ================= readout =================
  {
    int waves = N_WORD + N_DOC;
    int threads = waves * 64;
    final_kernel<<<(threads + 255) / 256, 256, 0, stream>>>(y, yd, lin_w, lin_b, out);
  }
}

// Round 3
// 1382.188 us; speedup vs baseline: 1.8669x; 1.8669x over previous
//
#include <hip/hip_runtime.h>
#include <math.h>

#define N_WORD 50000
#define N_DOC  10000
#define E_WW   800000
#define E_WD   320000
#define D_IN   256
#define D_H    128

// ---------------- SGEMM: C[M,N] = A[M,K] @ B[K,N], row-major, fp32 ----------
#define BM 64
#define BN 64
#define BK 16

__global__ __launch_bounds__(256) void sgemm_kernel(const float* __restrict__ A,
    const float* __restrict__ B, float* __restrict__ C, int M, int N, int K) {
  __shared__ float As[BK][BM + 1];
  __shared__ float Bs[BK][BN];
  const int tid = threadIdx.x;
  const int bm = blockIdx.y * BM;
  const int bn = blockIdx.x * BN;
  const int trow = (tid >> 4) << 2;
  const int tcol = (tid & 15) << 2;
  const int aRow = tid >> 2;
  const int aK   = (tid & 3) << 2;
  const int bK   = tid >> 4;
  const int bCol = (tid & 15) << 2;
  const bool aValid = (bm + aRow) < M;
  const int aRowC = aValid ? (bm + aRow) : (M - 1);
  const float* Aptr = A + (size_t)aRowC * K + aK;
  const float* Bptr = B + (size_t)bK * N + bn + bCol;

  float acc[4][4] = {};
  for (int k0 = 0; k0 < K; k0 += BK) {
    float4 av = make_float4(0.f, 0.f, 0.f, 0.f);
    if (aValid) av = *(const float4*)(Aptr + k0);
    float4 bv = *(const float4*)(Bptr + (size_t)k0 * N);
    As[aK + 0][aRow] = av.x;
    As[aK + 1][aRow] = av.y;
    As[aK + 2][aRow] = av.z;
    As[aK + 3][aRow] = av.w;
    *(float4*)&Bs[bK][bCol] = bv;
    __syncthreads();
#pragma unroll
    for (int k = 0; k < BK; ++k) {
      float ar[4], br[4];
#pragma unroll
      for (int i = 0; i < 4; ++i) ar[i] = As[k][trow + i];
#pragma unroll
      for (int j = 0; j < 4; ++j) br[j] = Bs[k][tcol + j];
#pragma unroll
      for (int i = 0; i < 4; ++i)
#pragma unroll
        for (int j = 0; j < 4; ++j) acc[i][j] += ar[i] * br[j];
    }
    __syncthreads();
  }
#pragma unroll
  for (int i = 0; i < 4; ++i) {
    int m = bm + trow + i;
    if (m < M) {
      float4 o = make_float4(acc[i][0], acc[i][1], acc[i][2], acc[i][3]);
      *(float4*)(C + (size_t)m * N + bn + tcol) = o;
    }
  }
}

// ---------------- CSR build --------------------------------------------------
__global__ void count_kernel(const int* __restrict__ dst, int* __restrict__ cnt, int E) {
  int i = blockIdx.x * blockDim.x + threadIdx.x;
  if (i < E) atomicAdd(&cnt[dst[i]], 1);
}

// in-place exclusive scan over a[0..n), writes total to a[n]; single block 1024 thr
__global__ __launch_bounds__(1024) void scan_kernel(int* __restrict__ a, int n) {
  __shared__ int sm[1024];
  int tid = threadIdx.x;
  int chunk = (n + 1023) >> 10;
  int lo = min(tid * chunk, n), hi = min(lo + chunk, n);
  int s = 0;
  for (int i = lo; i < hi; ++i) s += a[i];
  sm[tid] = s;
  __syncthreads();
  for (int off = 1; off < 1024; off <<= 1) {
    int v = (tid >= off) ? sm[tid - off] : 0;
    __syncthreads();
    sm[tid] += v;
    __syncthreads();
  }
  int run = sm[tid] - s;  // exclusive base of this chunk
  for (int i = lo; i < hi; ++i) {
    int c = a[i];          // alias-safe: read before overwrite
    a[i] = run;
    run += c;
  }
  if (tid == 1023) a[n] = sm[1023];
}

// consumes rp (rp[d] advances from start(d) to end(d)); src fits in uint16
__global__ void fill_kernel(const int* __restrict__ src, const int* __restrict__ dst,
                            int* __restrict__ rp, unsigned short* __restrict__ csr, int E) {
  int i = blockIdx.x * blockDim.x + threadIdx.x;
  if (i < E) {
    int pos = atomicAdd(&rp[dst[i]], 1);
    csr[pos] = (unsigned short)src[i];
  }
}

// ---------------- gather: one wave per dst node ------------------------------
// post-fill rp: beg = node? rp[node-1]:0, end = rp[node]
// mode 0: t[node] += mean
// mode 1: t[node] = relu(t[node] + mean + bias)
// mode 2: out[out_off+node] = sigmoid(dot(relu(t[node]+mean+bias), lw) + lb)
__global__ __launch_bounds__(256) void gather_kernel(
    const float* __restrict__ y, const unsigned short* __restrict__ csr,
    const int* __restrict__ rp, float* __restrict__ t,
    const float* __restrict__ bias, const float* __restrict__ lw,
    const float* __restrict__ lb, float* __restrict__ out,
    int n, int mode, int out_off) {
  int node = (blockIdx.x << 2) + (threadIdx.x >> 6);
  if (node >= n) return;
  int lane = threadIdx.x & 63;
  int beg = node ? rp[node - 1] : 0;
  int end = rp[node];
  float a0 = 0.f, a1 = 0.f;
  int j = beg;
  for (; j + 1 < end; j += 2) {           // 2-edge unroll for ILP
    int s0 = csr[j], s1 = csr[j + 1];
    const float* p0 = y + ((size_t)s0 << 7);
    const float* p1 = y + ((size_t)s1 << 7);
    float x0 = p0[lane], x1 = p0[lane + 64];
    float x2 = p1[lane], x3 = p1[lane + 64];
    a0 += x0 + x2;
    a1 += x1 + x3;
  }
  if (j < end) {
    const float* p0 = y + ((size_t)csr[j] << 7);
    a0 += p0[lane];
    a1 += p0[lane + 64];
  }
  int deg = end - beg;
  float inv = 1.0f / (float)(deg > 1 ? deg : 1);
  float* tp = t + ((size_t)node << 7);
  float f0 = tp[lane] + a0 * inv;
  float f1 = tp[lane + 64] + a1 * inv;
  if (mode == 0) {
    tp[lane] = f0;
    tp[lane + 64] = f1;
  } else {
    f0 += bias[lane];
    f1 += bias[lane + 64];
    f0 = f0 > 0.f ? f0 : 0.f;
    f1 = f1 > 0.f ? f1 : 0.f;
    if (mode == 1) {
      tp[lane] = f0;
      tp[lane + 64] = f1;
    } else {
      float s = f0 * lw[lane] + f1 * lw[lane + 64];
#pragma unroll
      for (int off = 32; off > 0; off >>= 1) s += __shfl_xor(s, off);
      if (lane == 0) out[out_off + node] = 1.0f / (1.0f + expf(-(s + lb[0])));
    }
  }
}

__global__ void add3_kernel(const float* __restrict__ a, const float* __restrict__ b,
                            const float* __restrict__ c, float* __restrict__ o, int n) {
  int i = blockIdx.x * blockDim.x + threadIdx.x;
  if (i < n) o[i] = a[i] + b[i] + c[i];
}

// ---------------------------------------------------------------------------
extern "C" void kernel_launch(void* const* d_in, const int* in_sizes, int n_in,
                              void* d_out, int out_size, void* d_ws, size_t ws_size,
                              hipStream_t stream) {
  const float* xw      = (const float*)d_in[0];
  const float* xd      = (const float*)d_in[1];
  const int*   ww_src  = (const int*)d_in[2];
  const int*   ww_dst  = (const int*)d_in[3];
  const int*   wwr_src = (const int*)d_in[4];
  const int*   wwr_dst = (const int*)d_in[5];
  const int*   wd_src  = (const int*)d_in[6];
  const int*   wd_dst  = (const int*)d_in[7];
  const int*   wdr_src = (const int*)d_in[8];
  const int*   wdr_dst = (const int*)d_in[9];
  const float* Ws1     = (const float*)d_in[10];  // [4,256,128]
  const float* Wn1     = (const float*)d_in[11];
  const float* b1      = (const float*)d_in[12];  // [4,128]
  const float* Ws2     = (const float*)d_in[13];  // [4,128,128]
  const float* Wn2     = (const float*)d_in[14];
  const float* b2      = (const float*)d_in[15];
  const float* lin_w   = (const float*)d_in[16];  // [128]
  const float* lin_b   = (const float*)d_in[17];  // [1]
  float* out = (float*)d_out;

  // ---- workspace carve (~92.4 MB) ----
  char* p = (char*)d_ws;
  auto alloc = [&](size_t nbytes) {
    char* r = p;
    p += (nbytes + 255) & ~(size_t)255;
    return r;
  };
  float* tw0 = (float*)alloc((size_t)N_WORD * D_H * 4);  // word acc / xw1
  float* tw1 = (float*)alloc((size_t)N_WORD * D_H * 4);  // layer-2 word acc
  float* yA  = (float*)alloc((size_t)N_WORD * D_H * 4);  // transformed word feats
  float* td0 = (float*)alloc((size_t)N_DOC * D_H * 4);   // doc acc / xd1
  float* td1 = (float*)alloc((size_t)N_DOC * D_H * 4);   // doc scratch / L2 doc acc
  unsigned short* csr_ww  = (unsigned short*)alloc((size_t)E_WW * 2);
  unsigned short* csr_wwr = (unsigned short*)alloc((size_t)E_WW * 2);
  unsigned short* csr_wdr = (unsigned short*)alloc((size_t)E_WD * 2);
  unsigned short* csr_wd  = (unsigned short*)alloc((size_t)E_WD * 2);
  int* rp_ww  = (int*)alloc((size_t)(N_WORD + 1) * 4);
  int* rp_wwr = (int*)alloc((size_t)(N_WORD + 1) * 4);
  int* rp_wdr = (int*)alloc((size_t)(N_WORD + 1) * 4);
  int* rp_wd  = (int*)alloc((size_t)(N_DOC + 1) * 4);
  float* Sw1 = (float*)alloc((size_t)D_IN * D_H * 4);
  float* Sw2 = (float*)alloc((size_t)D_H * D_H * 4);
  float* bs1 = (float*)alloc(D_H * 4);
  float* bs2 = (float*)alloc(D_H * 4);

  // ---- CSR build (counts -> in-place scan -> fill consuming rp) ----
  // NOTE: each rp array zeroed with its OWN memset — a single spanning memset
  // missed the 256B-alignment padding and left poison in rp_wd (round-2 crash).
  hipMemsetAsync(rp_ww,  0, (size_t)(N_WORD + 1) * 4, stream);
  hipMemsetAsync(rp_wwr, 0, (size_t)(N_WORD + 1) * 4, stream);
  hipMemsetAsync(rp_wdr, 0, (size_t)(N_WORD + 1) * 4, stream);
  hipMemsetAsync(rp_wd,  0, (size_t)(N_DOC + 1) * 4, stream);
  count_kernel<<<(E_WW + 255) / 256, 256, 0, stream>>>(ww_dst, rp_ww, E_WW);
  count_kernel<<<(E_WW + 255) / 256, 256, 0, stream>>>(wwr_dst, rp_wwr, E_WW);
  count_kernel<<<(E_WD + 255) / 256, 256, 0, stream>>>(wdr_dst, rp_wdr, E_WD);
  count_kernel<<<(E_WD + 255) / 256, 256, 0, stream>>>(wd_dst, rp_wd, E_WD);
  scan_kernel<<<1, 1024, 0, stream>>>(rp_ww, N_WORD);
  scan_kernel<<<1, 1024, 0, stream>>>(rp_wwr, N_WORD);
  scan_kernel<<<1, 1024, 0, stream>>>(rp_wdr, N_WORD);
  scan_kernel<<<1, 1024, 0, stream>>>(rp_wd, N_DOC);
  fill_kernel<<<(E_WW + 255) / 256, 256, 0, stream>>>(ww_src, ww_dst, rp_ww, csr_ww, E_WW);
  fill_kernel<<<(E_WW + 255) / 256, 256, 0, stream>>>(wwr_src, wwr_dst, rp_wwr, csr_wwr, E_WW);
  fill_kernel<<<(E_WD + 255) / 256, 256, 0, stream>>>(wdr_src, wdr_dst, rp_wdr, csr_wdr, E_WD);
  fill_kernel<<<(E_WD + 255) / 256, 256, 0, stream>>>(wd_src, wd_dst, rp_wd, csr_wd, E_WD);

  // ---- combined self-weights / biases for word target (rel 0,1,3) ----
  add3_kernel<<<(D_IN * D_H + 255) / 256, 256, 0, stream>>>(
      Ws1, Ws1 + 1 * D_IN * D_H, Ws1 + 3 * D_IN * D_H, Sw1, D_IN * D_H);
  add3_kernel<<<1, 128, 0, stream>>>(b1, b1 + 128, b1 + 384, bs1, 128);
  add3_kernel<<<(D_H * D_H + 255) / 256, 256, 0, stream>>>(
      Ws2, Ws2 + 1 * D_H * D_H, Ws2 + 3 * D_H * D_H, Sw2, D_H * D_H);
  add3_kernel<<<1, 128, 0, stream>>>(b2, b2 + 128, b2 + 384, bs2, 128);

  auto gemm = [&](const float* A, const float* Bm, float* C, int M, int K) {
    dim3 grid(D_H / BN, (M + BM - 1) / BM);
    sgemm_kernel<<<grid, dim3(256), 0, stream>>>(A, Bm, C, M, D_H, K);
  };
  auto gather = [&](const float* y, const unsigned short* csr, const int* rp, float* t,
                    const float* bias, int n, int mode, int out_off) {
    gather_kernel<<<(n + 3) / 4, 256, 0, stream>>>(y, csr, rp, t, bias, lin_w, lin_b,
                                                   out, n, mode, out_off);
  };

  const int W1 = D_IN * D_H;  // per-relation weight stride, layer 1
  const int W2 = D_H * D_H;   // layer 2

  // ================= layer 1 =================
  // word target: self (3 rels combined) + 3 neighbor means
  gemm(xw, Sw1, tw0, N_WORD, D_IN);
  gemm(xw, Wn1 + 0 * W1, yA, N_WORD, D_IN);
  gather(yA, csr_ww, rp_ww, tw0, nullptr, N_WORD, 0, 0);
  gemm(xw, Wn1 + 1 * W1, yA, N_WORD, D_IN);
  gather(yA, csr_wwr, rp_wwr, tw0, nullptr, N_WORD, 0, 0);
  gemm(xd, Wn1 + 3 * W1, td1, N_DOC, D_IN);                 // wdr: doc -> word
  gather(td1, csr_wdr, rp_wdr, tw0, bs1, N_WORD, 1, 0);     // + bias + relu -> xw1
  // doc target
  gemm(xd, Ws1 + 2 * W1, td0, N_DOC, D_IN);
  gemm(xw, Wn1 + 2 * W1, yA, N_WORD, D_IN);                 // wd: word -> doc
  gather(yA, csr_wd, rp_wd, td0, b1 + 256, N_DOC, 1, 0);    // -> xd1

  // ================= layer 2 (+ fused readout) =================
  gemm(tw0, Sw2, tw1, N_WORD, D_H);
  gemm(tw0, Wn2 + 0 * W2, yA, N_WORD, D_H);
  gather(yA, csr_ww, rp_ww, tw1, nullptr, N_WORD, 0, 0);
  gemm(tw0, Wn2 + 1 * W2, yA, N_WORD, D_H);
  gather(yA, csr_wwr, rp_wwr, tw1, nullptr, N_WORD, 0, 0);
  gemm(td0, Wn2 + 3 * W2, td1, N_DOC, D_H);
  gather(td1, csr_wdr, rp_wdr, tw1, bs2, N_WORD, 2, 0);     // word out -> out[0:N_WORD]
  gemm(td0, Ws2 + 2 * W2, td1, N_DOC, D_H);                 // reuse td1 as L2 doc acc
  gemm(tw0, Wn2 + 2 * W2, yA, N_WORD, D_H);
  gather(yA, csr_wd, rp_wd, td1, b2 + 256, N_DOC, 2, N_WORD);  // doc out
}

// Round 4
// 792.305 us; speedup vs baseline: 3.2568x; 1.7445x over previous
//
#include <hip/hip_runtime.h>
#include <math.h>

#define N_WORD 50000
#define N_DOC  10000
#define E_WW   800000
#define E_WD   320000
#define D_IN   256
#define D_H    128

typedef __attribute__((ext_vector_type(8))) short short8;
typedef __attribute__((ext_vector_type(4))) float f32x4;

__device__ inline short f2bf(float f) {  // fp32 -> bf16 bits, round-nearest-even
  unsigned u = __float_as_uint(f);
  u = (u + 0x7fffu + ((u >> 16) & 1u)) >> 16;
  return (short)u;
}

// ---------------- MFMA GEMM: C[M,128] = A[M,K](fp32) @ Bp(packed bf16) -------
// 256 thr = 4 waves; wave owns 16 rows x 128 cols (8 n-tiles), mfma 16x16x32.
// A converted fp32->bf16 in-register. Bp layout: [kt][nt][lane][8] contiguous.
__global__ __launch_bounds__(256) void mfma_gemm_kernel(
    const float* __restrict__ A, const short* __restrict__ Bp,
    float* __restrict__ C32, unsigned short* __restrict__ C16,
    int M, int K, int outBf16) {
  int wid = threadIdx.x >> 6;
  int lane = threadIdx.x & 63;
  int m0 = blockIdx.x * 64 + wid * 16;
  int mA = m0 + (lane & 15);
  if (mA >= M) mA = M - 1;           // clamp: garbage rows never stored
  int quad = lane >> 4;
  const float* arow = A + (size_t)mA * K + quad * 8;
  f32x4 acc[8];
#pragma unroll
  for (int nt = 0; nt < 8; ++nt) acc[nt] = (f32x4){0.f, 0.f, 0.f, 0.f};
  int KT = K >> 5;
  for (int kt = 0; kt < KT; ++kt) {
    float4 a0 = *(const float4*)(arow + kt * 32);
    float4 a1 = *(const float4*)(arow + kt * 32 + 4);
    short8 af;
    af[0] = f2bf(a0.x); af[1] = f2bf(a0.y); af[2] = f2bf(a0.z); af[3] = f2bf(a0.w);
    af[4] = f2bf(a1.x); af[5] = f2bf(a1.y); af[6] = f2bf(a1.z); af[7] = f2bf(a1.w);
    const short* bbase = Bp + ((size_t)kt * 8 * 512) + lane * 8;
#pragma unroll
    for (int nt = 0; nt < 8; ++nt) {
      short8 bf = *(const short8*)(bbase + (size_t)nt * 512);
      acc[nt] = __builtin_amdgcn_mfma_f32_16x16x32_bf16(af, bf, acc[nt], 0, 0, 0);
    }
  }
  // C/D layout: col = lane&15, row = quad*4 + r   [m89-verified]
  int ccol = lane & 15;
#pragma unroll
  for (int nt = 0; nt < 8; ++nt) {
#pragma unroll
    for (int r = 0; r < 4; ++r) {
      int row = m0 + quad * 4 + r;
      if (row < M) {
        if (outBf16)
          C16[(size_t)row * 128 + nt * 16 + ccol] = (unsigned short)f2bf(acc[nt][r]);
        else
          C32[(size_t)row * 128 + nt * 16 + ccol] = acc[nt][r];
      }
    }
  }
}

// ---------------- weight pack: fp32 [K,128] -> bf16 B-fragment layout --------
// l1 mats (K=256): 0:Ws1[0]+Ws1[1]+Ws1[3], 1..4:Wn1[0..3], 5:Ws1[2]
// l2 mats (K=128): same pattern from Ws2/Wn2.
__global__ void pack_w_kernel(const float* __restrict__ Ws1, const float* __restrict__ Wn1,
                              const float* __restrict__ Ws2, const float* __restrict__ Wn2,
                              short* __restrict__ Bp1, short* __restrict__ Bp2) {
  int tid = blockIdx.x * blockDim.x + threadIdx.x;
  const int L1T = 6 * 4096;   // 6 mats * 8kt * 8nt * 64 lanes
  const int L2T = 6 * 2048;
  if (tid >= L1T + L2T) return;
  const float *src0, *src1 = nullptr, *src2 = nullptr;
  short* dst;
  int kt, nt, lane;
  if (tid < L1T) {
    int mat = tid / 4096, rem = tid % 4096;
    kt = rem / 512; nt = (rem / 64) % 8; lane = rem % 64;
    const int W1 = 256 * 128;
    if (mat == 0) { src0 = Ws1; src1 = Ws1 + W1; src2 = Ws1 + 3 * W1; }
    else if (mat <= 4) src0 = Wn1 + (size_t)(mat - 1) * W1;
    else src0 = Ws1 + 2 * W1;
    dst = Bp1 + (size_t)mat * W1 + ((size_t)(kt * 8 + nt) * 64 + lane) * 8;
  } else {
    int t2 = tid - L1T;
    int mat = t2 / 2048, rem = t2 % 2048;
    kt = rem / 512; nt = (rem / 64) % 8; lane = rem % 64;
    const int W2 = 128 * 128;
    if (mat == 0) { src0 = Ws2; src1 = Ws2 + W2; src2 = Ws2 + 3 * W2; }
    else if (mat <= 4) src0 = Wn2 + (size_t)(mat - 1) * W2;
    else src0 = Ws2 + 2 * W2;
    dst = Bp2 + (size_t)mat * W2 + ((size_t)(kt * 8 + nt) * 64 + lane) * 8;
  }
  int n = nt * 16 + (lane & 15);
  int kb = kt * 32 + (lane >> 4) * 8;
  short8 v;
#pragma unroll
  for (int j = 0; j < 8; ++j) {
    float f = src0[(size_t)(kb + j) * 128 + n];
    if (src1) f += src1[(size_t)(kb + j) * 128 + n] + src2[(size_t)(kb + j) * 128 + n];
    v[j] = f2bf(f);
  }
  *(short8*)dst = v;
}

// ---------------- CSR build: fused counts, batched 3-phase scan, fused fill --
__global__ void count4_kernel(const int* __restrict__ wwd, const int* __restrict__ wwrd,
                              const int* __restrict__ wdrd, const int* __restrict__ wdd,
                              int* rww, int* rwwr, int* rwdr, int* rwd) {
  int i = blockIdx.x * blockDim.x + threadIdx.x;
  if (i < E_WW) atomicAdd(&rww[wwd[i]], 1);
  else if (i < 2 * E_WW) atomicAdd(&rwwr[wwrd[i - E_WW]], 1);
  else if (i < 2 * E_WW + E_WD) atomicAdd(&rwdr[wdrd[i - 2 * E_WW]], 1);
  else if (i < 2 * E_WW + 2 * E_WD) atomicAdd(&rwd[wdd[i - 2 * E_WW - E_WD]], 1);
}

#define SCHUNK 1024
#define NB_W 49          // ceil(50000/1024)
#define NB_D 10          // ceil(10000/1024)
#define NB_TOT (3 * NB_W + NB_D)

__device__ inline void scan_map(int b, int* rww, int* rwwr, int* rwdr, int* rwd,
                                int*& a, int& n, int& cb) {
  if (b < NB_W) { a = rww; n = N_WORD; cb = b; }
  else if (b < 2 * NB_W) { a = rwwr; n = N_WORD; cb = b - NB_W; }
  else if (b < 3 * NB_W) { a = rwdr; n = N_WORD; cb = b - 2 * NB_W; }
  else { a = rwd; n = N_DOC; cb = b - 3 * NB_W; }
}

__global__ __launch_bounds__(256) void scan_p1_kernel(int* rww, int* rwwr, int* rwdr,
                                                      int* rwd, int* partials) {
  int* a; int n, cb;
  scan_map(blockIdx.x, rww, rwwr, rwdr, rwd, a, n, cb);
  int base = cb * SCHUNK + threadIdx.x * 4;
  int s = 0;
#pragma unroll
  for (int j = 0; j < 4; ++j) { int i = base + j; if (i < n) s += a[i]; }
#pragma unroll
  for (int off = 32; off > 0; off >>= 1) s += __shfl_down(s, off);
  __shared__ int sm[4];
  if ((threadIdx.x & 63) == 0) sm[threadIdx.x >> 6] = s;
  __syncthreads();
  if (threadIdx.x == 0) partials[blockIdx.x] = sm[0] + sm[1] + sm[2] + sm[3];
}

__global__ __launch_bounds__(256) void scan_p2_kernel(int* partials) {
  __shared__ int sm[256];
  int tid = threadIdx.x;
  int v = (tid < NB_TOT) ? partials[tid] : 0;
  sm[tid] = v;
  __syncthreads();
  int base = tid < NB_W ? 0 : tid < 2 * NB_W ? NB_W
           : tid < 3 * NB_W ? 2 * NB_W : tid < NB_TOT ? 3 * NB_W : NB_TOT;
  for (int off = 1; off < 256; off <<= 1) {
    int add = (tid - off >= base) ? sm[tid - off] : 0;
    __syncthreads();
    sm[tid] += add;
    __syncthreads();
  }
  if (tid < NB_TOT) partials[tid] = sm[tid] - v;  // segmented exclusive
}

__global__ __launch_bounds__(256) void scan_p3_kernel(int* rww, int* rwwr, int* rwdr,
                                                      int* rwd, const int* __restrict__ partials) {
  int* a; int n, cb;
  scan_map(blockIdx.x, rww, rwwr, rwdr, rwd, a, n, cb);
  int base = cb * SCHUNK + threadIdx.x * 4;
  int c[4];
#pragma unroll
  for (int j = 0; j < 4; ++j) { int i = base + j; c[j] = (i < n) ? a[i] : 0; }
  int s = c[0] + c[1] + c[2] + c[3];
  __shared__ int sm[256];
  sm[threadIdx.x] = s;
  __syncthreads();
  for (int off = 1; off < 256; off <<= 1) {
    int add = (threadIdx.x >= off) ? sm[threadIdx.x - off] : 0;
    __syncthreads();
    sm[threadIdx.x] += add;
    __syncthreads();
  }
  int ex = sm[threadIdx.x] - s + partials[blockIdx.x];
#pragma unroll
  for (int j = 0; j < 4; ++j) {
    int i = base + j;
    if (i < n) a[i] = ex;
    ex += c[j];
  }
}

__global__ void fill4_kernel(const int* wws, const int* wwd, const int* wwrs, const int* wwrd,
                             const int* wdrs, const int* wdrd, const int* wds, const int* wdd,
                             int* rww, int* rwwr, int* rwdr, int* rwd,
                             unsigned short* cww, unsigned short* cwwr,
                             unsigned short* cwdr, unsigned short* cwd) {
  int i = blockIdx.x * blockDim.x + threadIdx.x;
  const int *src, *dst; int* rp; unsigned short* csr; int e;
  if (i < E_WW) { src = wws; dst = wwd; rp = rww; csr = cww; e = i; }
  else if (i < 2 * E_WW) { src = wwrs; dst = wwrd; rp = rwwr; csr = cwwr; e = i - E_WW; }
  else if (i < 2 * E_WW + E_WD) { src = wdrs; dst = wdrd; rp = rwdr; csr = cwdr; e = i - 2 * E_WW; }
  else if (i < 2 * E_WW + 2 * E_WD) { src = wds; dst = wdd; rp = rwd; csr = cwd; e = i - 2 * E_WW - E_WD; }
  else return;
  int pos = atomicAdd(&rp[dst[e]], 1);
  csr[pos] = (unsigned short)src[e];
}

// ---------------- gather: one wave per dst node; y is bf16, lane owns 2 chans
// mode 0: t += mean   mode 1: t = relu(t+mean+bias)
// mode 2: out[off+node] = sigmoid(dot(relu(t+mean+bias), lw) + lb)
__global__ __launch_bounds__(256) void gather_kernel(
    const unsigned int* __restrict__ y, const unsigned short* __restrict__ csr,
    const int* __restrict__ rp, float* __restrict__ t,
    const float* __restrict__ bias, const float* __restrict__ lw,
    const float* __restrict__ lb, float* __restrict__ out,
    int n, int mode, int out_off) {
  int node = (blockIdx.x << 2) + (threadIdx.x >> 6);
  if (node >= n) return;
  int lane = threadIdx.x & 63;
  int beg = node ? rp[node - 1] : 0;
  int end = rp[node];
  float a0 = 0.f, a1 = 0.f;
  int j = beg;
  for (; j + 3 < end; j += 4) {            // 4-edge unroll for MLP
    int s0 = csr[j], s1 = csr[j + 1], s2 = csr[j + 2], s3 = csr[j + 3];
    unsigned u0 = y[((size_t)s0 << 6) + lane];
    unsigned u1 = y[((size_t)s1 << 6) + lane];
    unsigned u2 = y[((size_t)s2 << 6) + lane];
    unsigned u3 = y[((size_t)s3 << 6) + lane];
    a0 += __uint_as_float(u0 << 16) + __uint_as_float(u1 << 16)
        + __uint_as_float(u2 << 16) + __uint_as_float(u3 << 16);
    a1 += __uint_as_float(u0 & 0xffff0000u) + __uint_as_float(u1 & 0xffff0000u)
        + __uint_as_float(u2 & 0xffff0000u) + __uint_as_float(u3 & 0xffff0000u);
  }
  for (; j < end; ++j) {
    unsigned u = y[((size_t)csr[j] << 6) + lane];
    a0 += __uint_as_float(u << 16);
    a1 += __uint_as_float(u & 0xffff0000u);
  }
  int deg = end - beg;
  float inv = 1.0f / (float)(deg > 1 ? deg : 1);
  float2* tp = (float2*)(t + ((size_t)node << 7)) + lane;
  float2 tv = *tp;
  float f0 = tv.x + a0 * inv;
  float f1 = tv.y + a1 * inv;
  if (mode == 0) {
    *tp = make_float2(f0, f1);
  } else {
    float2 bv = *((const float2*)bias + lane);
    f0 += bv.x; f1 += bv.y;
    f0 = f0 > 0.f ? f0 : 0.f;
    f1 = f1 > 0.f ? f1 : 0.f;
    if (mode == 1) {
      *tp = make_float2(f0, f1);
    } else {
      float2 lv = *((const float2*)lw + lane);
      float s = f0 * lv.x + f1 * lv.y;
#pragma unroll
      for (int off = 32; off > 0; off >>= 1) s += __shfl_xor(s, off);
      if (lane == 0) out[out_off + node] = 1.0f / (1.0f + expf(-(s + lb[0])));
    }
  }
}

__global__ void add3_kernel(const float* __restrict__ a, const float* __restrict__ b,
                            const float* __restrict__ c, float* __restrict__ o, int n) {
  int i = blockIdx.x * blockDim.x + threadIdx.x;
  if (i < n) o[i] = a[i] + b[i] + c[i];
}

// ---------------------------------------------------------------------------
extern "C" void kernel_launch(void* const* d_in, const int* in_sizes, int n_in,
                              void* d_out, int out_size, void* d_ws, size_t ws_size,
                              hipStream_t stream) {
  const float* xw      = (const float*)d_in[0];
  const float* xd      = (const float*)d_in[1];
  const int*   ww_src  = (const int*)d_in[2];
  const int*   ww_dst  = (const int*)d_in[3];
  const int*   wwr_src = (const int*)d_in[4];
  const int*   wwr_dst = (const int*)d_in[5];
  const int*   wd_src  = (const int*)d_in[6];
  const int*   wd_dst  = (const int*)d_in[7];
  const int*   wdr_src = (const int*)d_in[8];
  const int*   wdr_dst = (const int*)d_in[9];
  const float* Ws1     = (const float*)d_in[10];
  const float* Wn1     = (const float*)d_in[11];
  const float* b1      = (const float*)d_in[12];
  const float* Ws2     = (const float*)d_in[13];
  const float* Wn2     = (const float*)d_in[14];
  const float* b2      = (const float*)d_in[15];
  const float* lin_w   = (const float*)d_in[16];
  const float* lin_b   = (const float*)d_in[17];
  float* out = (float*)d_out;

  // ---- workspace carve (~83 MB) ----
  char* p = (char*)d_ws;
  auto alloc = [&](size_t nbytes) {
    char* r = p;
    p += (nbytes + 255) & ~(size_t)255;
    return r;
  };
  float* tw0 = (float*)alloc((size_t)N_WORD * D_H * 4);   // word acc / xw1
  float* tw1 = (float*)alloc((size_t)N_WORD * D_H * 4);   // layer-2 word acc
  float* td0 = (float*)alloc((size_t)N_DOC * D_H * 4);    // doc acc / xd1
  float* td2 = (float*)alloc((size_t)N_DOC * D_H * 4);    // layer-2 doc acc
  unsigned short* yB  = (unsigned short*)alloc((size_t)N_WORD * D_H * 2);  // bf16 y
  unsigned short* ydB = (unsigned short*)alloc((size_t)N_DOC * D_H * 2);
  unsigned short* csr_ww  = (unsigned short*)alloc((size_t)E_WW * 2);
  unsigned short* csr_wwr = (unsigned short*)alloc((size_t)E_WW * 2);
  unsigned short* csr_wdr = (unsigned short*)alloc((size_t)E_WD * 2);
  unsigned short* csr_wd  = (unsigned short*)alloc((size_t)E_WD * 2);
  int* rp_ww  = (int*)alloc((size_t)(N_WORD + 1) * 4);
  int* rp_wwr = (int*)alloc((size_t)(N_WORD + 1) * 4);
  int* rp_wdr = (int*)alloc((size_t)(N_WORD + 1) * 4);
  int* rp_wd  = (int*)alloc((size_t)(N_DOC + 1) * 4);
  short* Bp1 = (short*)alloc((size_t)6 * 256 * 128 * 2);
  short* Bp2 = (short*)alloc((size_t)6 * 128 * 128 * 2);
  int* partials = (int*)alloc((size_t)NB_TOT * 4);
  float* bs1 = (float*)alloc(D_H * 4);
  float* bs2 = (float*)alloc(D_H * 4);

  // ---- CSR build ----
  size_t rp_span = (size_t)((char*)rp_wd + (N_DOC + 1) * 4 - (char*)rp_ww);
  hipMemsetAsync(rp_ww, 0, rp_span, stream);  // spans pads too — all zeroed
  const int ETOT = 2 * E_WW + 2 * E_WD;
  count4_kernel<<<(ETOT + 255) / 256, 256, 0, stream>>>(
      ww_dst, wwr_dst, wdr_dst, wd_dst, rp_ww, rp_wwr, rp_wdr, rp_wd);
  scan_p1_kernel<<<NB_TOT, 256, 0, stream>>>(rp_ww, rp_wwr, rp_wdr, rp_wd, partials);
  scan_p2_kernel<<<1, 256, 0, stream>>>(partials);
  scan_p3_kernel<<<NB_TOT, 256, 0, stream>>>(rp_ww, rp_wwr, rp_wdr, rp_wd, partials);
  fill4_kernel<<<(ETOT + 255) / 256, 256, 0, stream>>>(
      ww_src, ww_dst, wwr_src, wwr_dst, wdr_src, wdr_dst, wd_src, wd_dst,
      rp_ww, rp_wwr, rp_wdr, rp_wd, csr_ww, csr_wwr, csr_wdr, csr_wd);

  // ---- weight pack + combined biases ----
  pack_w_kernel<<<(6 * 4096 + 6 * 2048 + 255) / 256, 256, 0, stream>>>(
      Ws1, Wn1, Ws2, Wn2, Bp1, Bp2);
  add3_kernel<<<1, 128, 0, stream>>>(b1, b1 + 128, b1 + 384, bs1, 128);
  add3_kernel<<<1, 128, 0, stream>>>(b2, b2 + 128, b2 + 384, bs2, 128);

  const int W1 = 256 * 128;  // packed per-matrix stride (shorts), layer 1
  const int W2 = 128 * 128;
  auto gemmF = [&](const float* A, const short* Bm, float* C, int M, int K) {
    mfma_gemm_kernel<<<(M + 63) / 64, 256, 0, stream>>>(A, Bm, C, nullptr, M, K, 0);
  };
  auto gemmH = [&](const float* A, const short* Bm, unsigned short* C, int M, int K) {
    mfma_gemm_kernel<<<(M + 63) / 64, 256, 0, stream>>>(A, Bm, nullptr, C, M, K, 1);
  };
  auto gather = [&](const unsigned short* y, const unsigned short* csr, const int* rp,
                    float* t, const float* bias, int n, int mode, int out_off) {
    gather_kernel<<<(n + 3) / 4, 256, 0, stream>>>((const unsigned int*)y, csr, rp, t,
                                                   bias, lin_w, lin_b, out, n, mode, out_off);
  };

  // ================= layer 1 =================
  gemmF(xw, Bp1 + 0 * W1, tw0, N_WORD, 256);                 // word self (3 rels combined)
  gemmH(xw, Bp1 + 1 * W1, yB, N_WORD, 256);                  // ww neigh
  gather(yB, csr_ww, rp_ww, tw0, nullptr, N_WORD, 0, 0);
  gemmH(xw, Bp1 + 2 * W1, yB, N_WORD, 256);                  // wwr neigh
  gather(yB, csr_wwr, rp_wwr, tw0, nullptr, N_WORD, 0, 0);
  gemmH(xd, Bp1 + 4 * W1, ydB, N_DOC, 256);                  // wdr: doc -> word
  gather(ydB, csr_wdr, rp_wdr, tw0, bs1, N_WORD, 1, 0);      // +bias+relu -> xw1
  gemmF(xd, Bp1 + 5 * W1, td0, N_DOC, 256);                  // doc self
  gemmH(xw, Bp1 + 3 * W1, yB, N_WORD, 256);                  // wd: word -> doc
  gather(yB, csr_wd, rp_wd, td0, b1 + 256, N_DOC, 1, 0);     // -> xd1

  // ================= layer 2 (+ fused readout) =================
  gemmF(tw0, Bp2 + 0 * W2, tw1, N_WORD, 128);
  gemmH(tw0, Bp2 + 1 * W2, yB, N_WORD, 128);
  gather(yB, csr_ww, rp_ww, tw1, nullptr, N_WORD, 0, 0);
  gemmH(tw0, Bp2 + 2 * W2, yB, N_WORD, 128);
  gather(yB, csr_wwr, rp_wwr, tw1, nullptr, N_WORD, 0, 0);
  gemmH(td0, Bp2 + 4 * W2, ydB, N_DOC, 128);
  gather(ydB, csr_wdr, rp_wdr, tw1, bs2, N_WORD, 2, 0);      // word out -> out[0:N_WORD]
  gemmF(td0, Bp2 + 5 * W2, td2, N_DOC, 128);
  gemmH(tw0, Bp2 + 3 * W2, yB, N_WORD, 128);
  gather(yB, csr_wd, rp_wd, td2, b2 + 256, N_DOC, 2, N_WORD);  // doc out
}